// Round 1
// baseline (846.663 us; speedup 1.0000x reference)
//
#include <hip/hip_runtime.h>

// DynamicGaussianBlur: [B=4, D=160, H=160, W=160, C=2] fp32, sigma [4,3],
// separable 3D gaussian, window 13 (radius 6), SAME zero padding.
// Three memory-bound passes: axis D (in->out), axis H (out->ws), axis W (ws->out).

#define BB 4
#define DD 160
#define HH 160
#define WW 160
#define CC 2
#define WSZ 13
#define RAD 6

constexpr int NPER_B = DD * HH * WW * CC;        // 8,192,000
constexpr int NTOT   = NPER_B * BB;              // 32,768,000  (< 2^31)
constexpr int ROW    = WW * CC;                  // 320
constexpr int PLANE  = HH * WW * CC;             // 51,200

template <int AXIS>
__global__ __launch_bounds__(256) void blur_pass(const float* __restrict__ in,
                                                 float* __restrict__ out,
                                                 const float* __restrict__ sigma) {
    __shared__ float wgt[WSZ];

    const int base0 = blockIdx.x * 256;          // block fully inside one batch (NPER_B % 256 == 0)
    const int b = base0 / NPER_B;

    if (threadIdx.x < WSZ) {
        const float sig = sigma[b * 3 + AXIS];
        const float loc = (float)threadIdx.x - (float)RAD;
        wgt[threadIdx.x] = expf(-(loc * loc) / (2.0f * sig * sig + 1e-7f));
    }
    __syncthreads();

    // normalization factor (broadcast LDS reads, no conflicts)
    float s = 0.0f;
#pragma unroll
    for (int k = 0; k < WSZ; ++k) s += wgt[k];
    const float inv = 1.0f / s;

    const int idx = base0 + threadIdx.x;

    // decompose flat index
    const int cw  = idx % ROW;                   // w*C + c
    const int rem = idx / ROW;
    const int h   = rem % HH;
    const int d   = (rem / HH) % DD;

    int p, stride;
    if (AXIS == 0)      { p = d;       stride = PLANE; }
    else if (AXIS == 1) { p = h;       stride = ROW;   }
    else                { p = cw >> 1; stride = CC;    }

    float acc = 0.0f;
#pragma unroll
    for (int k = 0; k < WSZ; ++k) {
        const int q = p + k - RAD;
        if (0 <= q && q < 160) {
            acc += wgt[k] * in[idx + (k - RAD) * stride];
        }
    }
    out[idx] = acc * inv;
}

extern "C" void kernel_launch(void* const* d_in, const int* in_sizes, int n_in,
                              void* d_out, int out_size, void* d_ws, size_t ws_size,
                              hipStream_t stream) {
    const float* img   = (const float*)d_in[0];
    const float* sigma = (const float*)d_in[1];
    float* out = (float*)d_out;
    float* tmp = (float*)d_ws;

    dim3 block(256);
    dim3 grid(NTOT / 256);

    // D axis: img -> out
    blur_pass<0><<<grid, block, 0, stream>>>(img, out, sigma);
    // H axis: out -> tmp
    blur_pass<1><<<grid, block, 0, stream>>>(out, tmp, sigma);
    // W axis: tmp -> out
    blur_pass<2><<<grid, block, 0, stream>>>(tmp, out, sigma);
}

// Round 2
// 512.081 us; speedup vs baseline: 1.6534x; 1.6534x over previous
//
#include <hip/hip_runtime.h>

// DynamicGaussianBlur: [B=4, D=160, H=160, W=160, C=2] fp32, sigma [4,3],
// separable 3D gaussian, window 13 (radius 6), SAME zero padding.
// Register sliding-window line-walk, float2 per thread (C pair / w pair).
// Passes: D (in->out), H (out->ws), W (ws->out).

#define WSZ 13
#define RAD 6
#define SEG 40        // axis segment per thread
#define NSEG 4        // 4 * 40 = 160
#define NAX 160

constexpr int BB = 4, DD = 160, HH = 160, WW = 160, CC = 2;
constexpr int R2 = WW;              // row length in float2 units   (160)
constexpr int P2 = HH * WW;         // plane in float2 units        (25,600)
constexpr int N2 = DD * HH * WW;    // batch in float2 units        (4,096,000)
constexpr int NCOL = BB * P2;       // columns per pass (float2)    (102,400)

template <int AXIS>
__global__ __launch_bounds__(256) void blur_walk(const float2* __restrict__ in,
                                                 float2* __restrict__ out,
                                                 const float* __restrict__ sigma) {
    const int cid = blockIdx.x * 256 + threadIdx.x;   // column id
    const int b   = cid / P2;                         // uniform per block
    const int rem = cid % P2;
    const int i1  = rem / 160;
    const int i2  = rem % 160;

    // per-thread normalized weights (13 expf per 40 outputs — negligible)
    const float sig  = sigma[b * 3 + AXIS];
    const float invd = 1.0f / (2.0f * sig * sig + 1e-7f);
    float w[WSZ];
    float s = 0.0f;
#pragma unroll
    for (int k = 0; k < WSZ; ++k) {
        const float loc = (float)(k - RAD);
        w[k] = expf(-loc * loc * invd);
        s += w[k];
    }
    const float inv = 1.0f / s;
#pragma unroll
    for (int k = 0; k < WSZ; ++k) w[k] *= inv;

    int base2, st;
    if (AXIS == 0)      { base2 = b * N2 + i1 * R2 + i2;  st = P2; }  // walk d; (h,w) fixed
    else if (AXIS == 1) { base2 = b * N2 + i1 * P2 + i2;  st = R2; }  // walk h; (d,w) fixed
    else                { base2 = b * N2 + i1 * P2 + i2 * R2; st = 1; } // walk w; (d,h) fixed

    const int p0 = blockIdx.y * SEG;

    // preload window for first output position p0: positions p0-6 .. p0+6
    float wx[WSZ], wy[WSZ];
#pragma unroll
    for (int k = 0; k < WSZ; ++k) {
        const int q = p0 - RAD + k;
        float2 v = make_float2(0.0f, 0.0f);
        if (q >= 0 && q < NAX) v = in[base2 + q * st];
        wx[k] = v.x; wy[k] = v.y;
    }

#pragma unroll 4
    for (int i = 0; i < SEG; ++i) {
        float ax = 0.0f, ay = 0.0f;
#pragma unroll
        for (int k = 0; k < WSZ; ++k) { ax += w[k] * wx[k]; ay += w[k] * wy[k]; }
        out[base2 + (p0 + i) * st] = make_float2(ax, ay);

        // slide: bring in position p0+i+7 (uniform branch; zero outside volume)
#pragma unroll
        for (int k = 0; k < WSZ - 1; ++k) { wx[k] = wx[k + 1]; wy[k] = wy[k + 1]; }
        const int q = p0 + i + RAD + 1;
        float2 v = make_float2(0.0f, 0.0f);
        if (q < NAX) v = in[base2 + q * st];
        wx[WSZ - 1] = v.x; wy[WSZ - 1] = v.y;
    }
}

extern "C" void kernel_launch(void* const* d_in, const int* in_sizes, int n_in,
                              void* d_out, int out_size, void* d_ws, size_t ws_size,
                              hipStream_t stream) {
    const float2* img   = (const float2*)d_in[0];
    const float*  sigma = (const float*)d_in[1];
    float2* out = (float2*)d_out;
    float2* tmp = (float2*)d_ws;

    dim3 block(256);
    dim3 grid(NCOL / 256, NSEG);   // (400, 4)

    blur_walk<0><<<grid, block, 0, stream>>>(img, out, sigma);  // D: in  -> out
    blur_walk<1><<<grid, block, 0, stream>>>(out, tmp, sigma);  // H: out -> ws
    blur_walk<2><<<grid, block, 0, stream>>>(tmp, out, sigma);  // W: ws  -> out
}

// Round 3
// 159.703 us; speedup vs baseline: 5.3015x; 3.2065x over previous
//
#include <hip/hip_runtime.h>

// DynamicGaussianBlur: [B=4, D=160, H=160, W=160, C=2] fp32, sigma [4,3],
// separable 3D gaussian, window 13 (radius 6), SAME zero padding.
// D,H: register sliding-window line-walk (coalesced across w).
// W:   LDS row-staged blur (walk axis == contiguous axis, so stage rows).

#define WSZ 13
#define RAD 6
#define SEG 40        // axis segment per thread (D/H walk)
#define NSEG 4
#define NAX 160

constexpr int BB = 4, DD = 160, HH = 160, WW = 160, CC = 2;
constexpr int R2 = WW;              // row length in float2 units   (160)
constexpr int P2 = HH * WW;         // plane in float2 units        (25,600)
constexpr int N2 = DD * HH * WW;    // batch in float2 units        (4,096,000)
constexpr int NCOL = BB * P2;       // columns per D/H pass         (102,400)
constexpr int NROW = BB * DD * HH;  // rows for W pass              (102,400)
constexpr int ROWS_PER_BLK = 8;

__device__ __forceinline__ void make_weights(float sig, float* w) {
    const float invd = 1.0f / (2.0f * sig * sig + 1e-7f);
    float s = 0.0f;
#pragma unroll
    for (int k = 0; k < WSZ; ++k) {
        const float loc = (float)(k - RAD);
        w[k] = __expf(-loc * loc * invd);
        s += w[k];
    }
    const float inv = 1.0f / s;
#pragma unroll
    for (int k = 0; k < WSZ; ++k) w[k] *= inv;
}

template <int AXIS>
__global__ __launch_bounds__(256) void blur_walk(const float2* __restrict__ in,
                                                 float2* __restrict__ out,
                                                 const float* __restrict__ sigma) {
    const int cid = blockIdx.x * 256 + threadIdx.x;   // column id
    const int b   = cid / P2;                         // uniform per block
    const int rem = cid % P2;
    const int i1  = rem / 160;
    const int i2  = rem % 160;

    float w[WSZ];
    make_weights(sigma[b * 3 + AXIS], w);

    int base2, st;
    if (AXIS == 0)      { base2 = b * N2 + i1 * R2 + i2;  st = P2; }  // walk d
    else                { base2 = b * N2 + i1 * P2 + i2;  st = R2; }  // walk h

    const int p0 = blockIdx.y * SEG;

    float wx[WSZ], wy[WSZ];
#pragma unroll
    for (int k = 0; k < WSZ; ++k) {
        const int q = p0 - RAD + k;
        float2 v = make_float2(0.0f, 0.0f);
        if (q >= 0 && q < NAX) v = in[base2 + q * st];
        wx[k] = v.x; wy[k] = v.y;
    }

#pragma unroll 4
    for (int i = 0; i < SEG; ++i) {
        float ax = 0.0f, ay = 0.0f;
#pragma unroll
        for (int k = 0; k < WSZ; ++k) { ax += w[k] * wx[k]; ay += w[k] * wy[k]; }
        out[base2 + (p0 + i) * st] = make_float2(ax, ay);

#pragma unroll
        for (int k = 0; k < WSZ - 1; ++k) { wx[k] = wx[k + 1]; wy[k] = wy[k + 1]; }
        const int q = p0 + i + RAD + 1;
        float2 v = make_float2(0.0f, 0.0f);
        if (q < NAX) v = in[base2 + q * st];
        wx[WSZ - 1] = v.x; wy[WSZ - 1] = v.y;
    }
}

// W-axis pass: stage ROWS_PER_BLK contiguous rows in LDS, blur along w.
__global__ __launch_bounds__(256) void blur_w(const float2* __restrict__ in,
                                              float2* __restrict__ out,
                                              const float* __restrict__ sigma) {
    __shared__ float2 lds[ROWS_PER_BLK][R2];

    const int tid  = threadIdx.x;
    const int rowBase = blockIdx.x * ROWS_PER_BLK;      // first row of this block
    const int base2   = rowBase * R2;                   // float2 offset
    const int b = rowBase / (DD * HH);                  // uniform (25,600 rows/batch % 8 == 0)

    float w[WSZ];
    make_weights(sigma[b * 3 + 2], w);

    // coalesced stage: 1280 float2, 256 threads, 5 each
#pragma unroll
    for (int j = 0; j < ROWS_PER_BLK * R2 / 256; ++j) {
        const int idx = j * 256 + tid;
        lds[idx / R2][idx % R2] = in[base2 + idx];
    }
    __syncthreads();

    const int r  = tid >> 5;        // row within block (0..7)
    const int w0 = tid & 31;        // lane's first w position

#pragma unroll
    for (int j = 0; j < R2 / 32; ++j) {
        const int x = w0 + 32 * j;
        float ax = 0.0f, ay = 0.0f;
#pragma unroll
        for (int k = 0; k < WSZ; ++k) {
            const int q = x - RAD + k;
            if (q >= 0 && q < R2) {
                const float2 v = lds[r][q];
                ax += w[k] * v.x; ay += w[k] * v.y;
            }
        }
        out[base2 + r * R2 + x] = make_float2(ax, ay);
    }
}

extern "C" void kernel_launch(void* const* d_in, const int* in_sizes, int n_in,
                              void* d_out, int out_size, void* d_ws, size_t ws_size,
                              hipStream_t stream) {
    const float2* img   = (const float2*)d_in[0];
    const float*  sigma = (const float*)d_in[1];
    float2* out = (float2*)d_out;
    float2* tmp = (float2*)d_ws;

    dim3 block(256);
    dim3 gridW(NCOL / 256, NSEG);   // (400, 4)

    blur_walk<0><<<gridW, block, 0, stream>>>(img, out, sigma);      // D: in  -> out
    blur_walk<1><<<gridW, block, 0, stream>>>(out, tmp, sigma);      // H: out -> ws
    blur_w<<<dim3(NROW / ROWS_PER_BLK), block, 0, stream>>>(tmp, out, sigma);  // W: ws -> out
}